// Round 19
// baseline (219.185 us; speedup 1.0000x reference)
//
#include <hip/hip_runtime.h>

#define C_IN   64
#define C_OUT  128
#define Himg   128
#define Wimg   128
#define HW     (Himg * Wimg)
#define TROWS  4
#define TCOLS  32
#define HROWS  6
#define HCOLS  34
#define XKSTR  (HROWS * HCOLS * 16)
#define WS_TAP 16384

// padded bf16 cell image: [img][kg 8][y' 130][x' 130] cells of 8 ch (16 B)
#define XB_CIMG  (8 * 130 * 130)             // cells per image
#define XB_OFF   163840                      // xb starts after wt in d_ws
#define WS_NEED  (XB_OFF + (size_t)36 * XB_CIMG * 16)

typedef __bf16 bf16x8 __attribute__((ext_vector_type(8)));
typedef float  f32x16 __attribute__((ext_vector_type(16)));

__device__ __forceinline__ unsigned int pack2(float a, float b) {
  union { __bf16 h; unsigned short s; } ua, ub;
  ua.h = (__bf16)a; ub.h = (__bf16)b;
  return (unsigned int)ua.s | ((unsigned int)ub.s << 16);
}

__device__ __forceinline__ void gload_lds16(const void* g, void* l) {
  __builtin_amdgcn_global_load_lds((const __attribute__((address_space(1))) void*)g,
                                   (__attribute__((address_space(3))) void*)l, 16, 0, 0);
}

// fp32 W[co][c][3][3] -> bf16 wt, [tap][kidx][co128][ch8] 16B cells (R18 layout, verified)
__global__ void wt_transform(const float* __restrict__ w, unsigned short* __restrict__ wt) {
  const int idx = blockIdx.x * 256 + threadIdx.x;
  if (idx >= 9 * C_OUT * C_IN) return;
  const int c   = idx & 63;
  const int co  = (idx >> 6) & 127;
  const int tap = idx >> 13;
  const int ky = tap / 3, kx = tap % 3;
  const float f = w[((co * C_IN + c) * 3 + ky) * 3 + kx];
  union { __bf16 h; unsigned short s; } u; u.h = (__bf16)f;
  wt[tap * 8192 + (c >> 3) * 1024 + co * 8 + (c & 7)] = u.s;
}

// fp32 x[img][c][y][x] -> padded bf16 cells xb[img][kg][y'][x'] (R10 layout, verified)
__global__ void xcvt(const float* __restrict__ xin, unsigned short* __restrict__ xb) {
  const int idx = blockIdx.x * 256 + threadIdx.x;
  if (idx >= 36 * 8 * 130 * 130) return;
  const int xp  = idx % 130;
  const int yp  = (idx / 130) % 130;
  const int kg  = (idx / (130 * 130)) & 7;
  const int img = idx / (130 * 130 * 8);
  const int x = xp - 1, y = yp - 1;
  float f[8] = {0.f, 0.f, 0.f, 0.f, 0.f, 0.f, 0.f, 0.f};
  if (x >= 0 && x < Wimg && y >= 0 && y < Himg) {
    const float* p = xin + ((size_t)img * C_IN + kg * 8) * HW + (size_t)y * Wimg + x;
    #pragma unroll
    for (int j = 0; j < 8; ++j) f[j] = p[(size_t)j * HW];
  }
  uint4 cell;
  cell.x = pack2(f[0], f[1]); cell.y = pack2(f[2], f[3]);
  cell.z = pack2(f[4], f[5]); cell.w = pack2(f[6], f[7]);
  *(uint4*)(xb + (size_t)idx * 8) = cell;
}

// ---------------- main conv: B direct from global xb, A from LDS dbuf ----------------
__global__ __launch_bounds__(256, 3)
void conv_xb(const unsigned short* __restrict__ xb, const unsigned short* __restrict__ wt,
             const float* __restrict__ bias, float* __restrict__ out) {
  __shared__ __align__(16) unsigned char Ws[2][WS_TAP];   // 32768 total: 3+ blocks/CU

  const int tid = threadIdx.x;
  // bijective XCD swizzle: 4608 = 8 * 576
  const int wg  = (blockIdx.x & 7) * 576 + (blockIdx.x >> 3);
  const int bx  = wg & 3;
  const int by  = (wg >> 2) & 31;
  const int img = wg >> 7;
  const int gy0 = by * TROWS;
  const int gx0 = bx * TCOLS;
  const int lane = tid & 63;
  const int wv   = tid >> 6;   // 0..3
  const int lpx  = lane & 31;
  const int lkh  = lane >> 5;
  const int wm   = wv & 1;     // co 64-half
  const int wn   = wv >> 1;    // 0..1: row-pair

  // ---- issue async Ws tap-0 DMA ----
  #pragma unroll
  for (int j = 0; j < 4; ++j)
    gload_lds16(wt + j * 2048 + tid * 8, &Ws[0][j * 4096 + tid * 16]);

  // per-lane B cell base: cell(img, kg=lkh, y'=gy0+wn*2, x'=gx0+lpx)
  const unsigned char* xbb = (const unsigned char*)xb;
  const size_t cb = ((size_t)(img * 8 + lkh) * 130 + (gy0 + wn * 2)) * 130 + gx0 + lpx;

  f32x16 acc[2][2];
  #pragma unroll
  for (int mf = 0; mf < 2; ++mf)
    #pragma unroll
    for (int nf = 0; nf < 2; ++nf)
      acc[mf][nf] = (f32x16)(0.f);

  const int abase = lkh * 2048 + (wm * 64 + lpx) * 16;

  __syncthreads();   // Ws[0] ready (drains DMA)

  for (int t = 0; t < 9; ++t) {
    if (t < 8) {   // async-prefetch tap t+1
      const unsigned short* sn = wt + (t + 1) * 8192 + tid * 8;
      unsigned char* db = Ws[(t + 1) & 1];
      #pragma unroll
      for (int j = 0; j < 4; ++j)
        gload_lds16(sn + j * 2048, &db[j * 4096 + tid * 16]);
    }
    const int dy = (t >= 6) ? 2 : (t >= 3 ? 1 : 0);
    const int dx = t - dy * 3;
    const unsigned char* wsb = Ws[t & 1];
    const size_t cofs = cb + (size_t)(dy * 130 + dx);
    #pragma unroll
    for (int ks = 0; ks < 4; ++ks) {
      bf16x8 A0 = *(const bf16x8*)&wsb[abase + ks * 4096];
      bf16x8 A1 = *(const bf16x8*)&wsb[abase + ks * 4096 + 512];
      const size_t c0 = cofs + (size_t)ks * (2 * 130 * 130);
      bf16x8 B0 = *(const bf16x8*)(xbb + c0 * 16);
      bf16x8 B1 = *(const bf16x8*)(xbb + (c0 + 130) * 16);
      __builtin_amdgcn_s_setprio(1);
      acc[0][0] = __builtin_amdgcn_mfma_f32_32x32x16_bf16(A0, B0, acc[0][0], 0, 0, 0);
      acc[0][1] = __builtin_amdgcn_mfma_f32_32x32x16_bf16(A0, B1, acc[0][1], 0, 0, 0);
      acc[1][0] = __builtin_amdgcn_mfma_f32_32x32x16_bf16(A1, B0, acc[1][0], 0, 0, 0);
      acc[1][1] = __builtin_amdgcn_mfma_f32_32x32x16_bf16(A1, B1, acc[1][1], 0, 0, 0);
      __builtin_amdgcn_s_setprio(0);
    }
    if (t < 8) __syncthreads();
  }

  // ---- epilogue: bias + fp32 full-line stores (R18 verbatim) ----
  #pragma unroll
  for (int nf = 0; nf < 2; ++nf) {
    const int y = gy0 + wn * 2 + nf;
    float* op = out + (size_t)img * C_OUT * HW + (size_t)y * Wimg + gx0 + lpx;
    #pragma unroll
    for (int mf = 0; mf < 2; ++mf) {
      #pragma unroll
      for (int rq = 0; rq < 4; ++rq) {
        const float4 bb = *(const float4*)(bias + wm * 64 + mf * 32 + rq * 8 + lkh * 4);
        #pragma unroll
        for (int j = 0; j < 4; ++j) {
          const int r  = rq * 4 + j;
          const int co = wm * 64 + mf * 32 + j + 8 * rq + lkh * 4;
          op[(size_t)co * HW] = acc[mf][nf][r] + (&bb.x)[j];
        }
      }
    }
  }
}

// ---------------- fallback: R18 kernel (fp32 in-kernel staging) ----------------
__global__ __launch_bounds__(256, 2)
void conv_fb(const float* __restrict__ xin, const unsigned short* __restrict__ wt,
             const float* __restrict__ bias, float* __restrict__ out) {
  __shared__ __align__(16) unsigned char Xs[8 * XKSTR];
  __shared__ __align__(16) unsigned char Ws[2][WS_TAP];

  const int tid = threadIdx.x;
  const int wg  = (blockIdx.x & 7) * 576 + (blockIdx.x >> 3);
  const int bx  = wg & 3;
  const int by  = (wg >> 2) & 31;
  const int img = wg >> 7;
  const int gy0 = by * TROWS;
  const int gx0 = bx * TCOLS;
  const int lane = tid & 63;
  const int wv   = tid >> 6;
  const int lpx  = lane & 31;
  const int lkh  = lane >> 5;
  const int wm   = wv & 1;
  const int wn   = wv >> 1;

  #pragma unroll
  for (int j = 0; j < 4; ++j)
    gload_lds16(wt + j * 2048 + tid * 8, &Ws[0][j * 4096 + tid * 16]);

  const int xi = tid & 31;
  const int kg = tid >> 5;
  float xr[HROWS][8];
  {
    const float* pb = xin + ((size_t)img * C_IN + kg * 8) * HW + gx0 + xi;
    #pragma unroll
    for (int r = 0; r < HROWS; ++r) {
      const int gy = gy0 - 1 + r;
      if (gy >= 0 && gy < Himg) {
        const float* p = pb + (size_t)gy * Wimg;
        #pragma unroll
        for (int ch = 0; ch < 8; ++ch) xr[r][ch] = p[(size_t)ch * HW];
      } else {
        #pragma unroll
        for (int ch = 0; ch < 8; ++ch) xr[r][ch] = 0.f;
      }
    }
  }
  float hr[8];
  const int hside = (tid >= 48) ? 1 : 0;
  const int hrem  = tid - hside * 48;
  const int hrow  = hrem >> 3;
  const int hkg   = hrem & 7;
  if (tid < 96) {
    const int gx = hside ? gx0 + TCOLS : gx0 - 1;
    const int gy = gy0 - 1 + hrow;
    if (gy >= 0 && gy < Himg && gx >= 0 && gx < Wimg) {
      const float* p = xin + ((size_t)img * C_IN + hkg * 8) * HW + (size_t)gy * Wimg + gx;
      #pragma unroll
      for (int ch = 0; ch < 8; ++ch) hr[ch] = p[(size_t)ch * HW];
    } else {
      #pragma unroll
      for (int ch = 0; ch < 8; ++ch) hr[ch] = 0.f;
    }
  }
  #pragma unroll
  for (int r = 0; r < HROWS; ++r) {
    uint4 cell;
    cell.x = pack2(xr[r][0], xr[r][1]); cell.y = pack2(xr[r][2], xr[r][3]);
    cell.z = pack2(xr[r][4], xr[r][5]); cell.w = pack2(xr[r][6], xr[r][7]);
    *(uint4*)(&Xs[kg * XKSTR + (r * HCOLS + 1 + xi) * 16]) = cell;
  }
  if (tid < 96) {
    uint4 cell;
    cell.x = pack2(hr[0], hr[1]); cell.y = pack2(hr[2], hr[3]);
    cell.z = pack2(hr[4], hr[5]); cell.w = pack2(hr[6], hr[7]);
    *(uint4*)(&Xs[hkg * XKSTR + (hrow * HCOLS + (hside ? HCOLS - 1 : 0)) * 16]) = cell;
  }

  f32x16 acc[2][2];
  #pragma unroll
  for (int mf = 0; mf < 2; ++mf)
    #pragma unroll
    for (int nf = 0; nf < 2; ++nf)
      acc[mf][nf] = (f32x16)(0.f);

  __syncthreads();

  for (int t = 0; t < 9; ++t) {
    if (t < 8) {
      const unsigned short* sn = wt + (t + 1) * 8192 + tid * 8;
      unsigned char* db = Ws[(t + 1) & 1];
      #pragma unroll
      for (int j = 0; j < 4; ++j)
        gload_lds16(sn + j * 2048, &db[j * 4096 + tid * 16]);
    }
    const int dy = (t >= 6) ? 2 : (t >= 3 ? 1 : 0);
    const int dx = t - dy * 3;
    const unsigned char* wsb = Ws[t & 1];
    int boff[2];
    #pragma unroll
    for (int nf = 0; nf < 2; ++nf)
      boff[nf] = lkh * XKSTR + ((wn * 2 + nf + dy) * HCOLS + dx + lpx) * 16;
    const int abase = lkh * 2048 + (wm * 64 + lpx) * 16;
    #pragma unroll
    for (int ks = 0; ks < 4; ++ks) {
      bf16x8 A0 = *(const bf16x8*)&wsb[abase + ks * 4096];
      bf16x8 A1 = *(const bf16x8*)&wsb[abase + ks * 4096 + 512];
      bf16x8 B0 = *(const bf16x8*)&Xs[boff[0] + ks * 2 * XKSTR];
      bf16x8 B1 = *(const bf16x8*)&Xs[boff[1] + ks * 2 * XKSTR];
      acc[0][0] = __builtin_amdgcn_mfma_f32_32x32x16_bf16(A0, B0, acc[0][0], 0, 0, 0);
      acc[0][1] = __builtin_amdgcn_mfma_f32_32x32x16_bf16(A0, B1, acc[0][1], 0, 0, 0);
      acc[1][0] = __builtin_amdgcn_mfma_f32_32x32x16_bf16(A1, B0, acc[1][0], 0, 0, 0);
      acc[1][1] = __builtin_amdgcn_mfma_f32_32x32x16_bf16(A1, B1, acc[1][1], 0, 0, 0);
    }
    if (t < 8) __syncthreads();
  }

  #pragma unroll
  for (int nf = 0; nf < 2; ++nf) {
    const int y = gy0 + wn * 2 + nf;
    float* op = out + (size_t)img * C_OUT * HW + (size_t)y * Wimg + gx0 + lpx;
    #pragma unroll
    for (int mf = 0; mf < 2; ++mf) {
      #pragma unroll
      for (int rq = 0; rq < 4; ++rq) {
        const float4 bb = *(const float4*)(bias + wm * 64 + mf * 32 + rq * 8 + lkh * 4);
        #pragma unroll
        for (int j = 0; j < 4; ++j) {
          const int r  = rq * 4 + j;
          const int co = wm * 64 + mf * 32 + j + 8 * rq + lkh * 4;
          op[(size_t)co * HW] = acc[mf][nf][r] + (&bb.x)[j];
        }
      }
    }
  }
}

extern "C" void kernel_launch(void* const* d_in, const int* in_sizes, int n_in,
                              void* d_out, int out_size, void* d_ws, size_t ws_size,
                              hipStream_t stream) {
  const float* x    = (const float*)d_in[0];
  const float* w    = (const float*)d_in[1];
  const float* bias = (const float*)d_in[2];
  float* out = (float*)d_out;
  unsigned short* wt = (unsigned short*)d_ws;                    // 147456 B
  unsigned short* xb = (unsigned short*)((char*)d_ws + XB_OFF);  // 77.8 MB padded bf16 cells

  wt_transform<<<(9 * C_OUT * C_IN + 255) / 256, 256, 0, stream>>>(w, wt);

  if (ws_size >= WS_NEED) {
    const int ncell = 36 * 8 * 130 * 130;
    xcvt<<<(ncell + 255) / 256, 256, 0, stream>>>(x, xb);
    conv_xb<<<dim3(4608), 256, 0, stream>>>(xb, wt, bias, out);
  } else {
    conv_fb<<<dim3(4608), 256, 0, stream>>>(x, wt, bias, out);
  }
}

// Round 21
// 177.726 us; speedup vs baseline: 1.2333x; 1.2333x over previous
//
#include <hip/hip_runtime.h>

#define C_IN   64
#define C_OUT  128
#define Himg   128
#define Wimg   128
#define HW     (Himg * Wimg)
#define TROWS  4
#define TCOLS  64
#define HROWS  6    // TROWS+2
#define HCOLS  66   // TCOLS+2
#define XCELLS (HROWS * HCOLS)   // 396
#define XKSTR  (XCELLS * 16)     // 6336 B per kidx row
#define WS_COH 73728             // 9 taps * 8 kidx * 64 co * 16 B

typedef __bf16 bf16x8 __attribute__((ext_vector_type(8)));
typedef float  f32x16 __attribute__((ext_vector_type(16)));

__device__ __forceinline__ unsigned int pack2(float a, float b) {
  union { __bf16 h; unsigned short s; } ua, ub;
  ua.h = (__bf16)a; ub.h = (__bf16)b;
  return (unsigned int)ua.s | ((unsigned int)ub.s << 16);
}

__device__ __forceinline__ void gload_lds16(const void* g, void* l) {
  __builtin_amdgcn_global_load_lds((const __attribute__((address_space(1))) void*)g,
                                   (__attribute__((address_space(3))) void*)l, 16, 0, 0);
}

// fp32 W[co][c][3][3] -> bf16 wt, [coh][tap][kidx][co64][ch8] 16B cells (verified R12)
__global__ void wt_transform(const float* __restrict__ w, unsigned short* __restrict__ wt) {
  const int idx = blockIdx.x * 256 + threadIdx.x;
  if (idx >= 9 * C_OUT * C_IN) return;
  const int c   = idx & 63;
  const int co  = (idx >> 6) & 127;
  const int tap = idx >> 13;
  const int ky = tap / 3, kx = tap % 3;
  const float f = w[((co * C_IN + c) * 3 + ky) * 3 + kx];
  union { __bf16 h; unsigned short s; } u; u.h = (__bf16)f;
  const int coh = co >> 6, col = co & 63;
  wt[(((coh * 9 + tap) * 8) + (c >> 3)) * 512 + col * 8 + (c & 7)] = u.s;
}

__global__ __launch_bounds__(512, 2)
void conv_mfma(const float* __restrict__ xin, const unsigned short* __restrict__ wt,
               const float* __restrict__ bias, float* __restrict__ out) {
  __shared__ __align__(16) unsigned char Xs[8 * XKSTR];   // 50688: [kidx][row6][col66] cells
  __shared__ __align__(16) unsigned char Ws[WS_COH];      // 73728  (total 124416)

  const int tid = threadIdx.x;
  const int bid = blockIdx.x;          // 512 blocks
  const int xcd = bid & 7;
  const int bi  = bid >> 3;            // 0..63
  const int coh = bi & 1;
  const int s   = xcd * 32 + (bi >> 1);  // 0..255: 9-tile strip id

  const int lane = tid & 63;
  const int wv   = tid >> 6;   // 0..7
  const int lpx  = lane & 31;
  const int lkh  = lane >> 5;
  const int wm   = wv & 1;     // co 32-half within coh slice
  const int wn   = wv >> 1;    // 0..3: row

  // staging roles: interior = (xi 64) x (kq 8); halo cols for tid<96
  const int xi = tid & 63;
  const int kq = tid >> 6;
  const int hside = (tid >= 48) ? 1 : 0;
  const int hrem  = tid - hside * 48;
  const int hrow  = hrem >> 3;     // 0..5
  const int hkg   = hrem & 7;

  // ---- Ws DMA: entire coh weight slice, once per block ----
  {
    const unsigned short* s0 = wt + coh * 36864 + tid * 8;
    #pragma unroll
    for (int j = 0; j < 9; ++j)
      gload_lds16(s0 + j * 4096, &Ws[tid * 16 + j * 8192]);
  }

  float xr[HROWS][8];
  float hr[8];

  auto LOADX = [&](int img, int gy0, int gx0) {
    const float* pb = xin + ((size_t)img * C_IN + kq * 8) * HW + gx0 + xi;
    #pragma unroll
    for (int r = 0; r < HROWS; ++r) {
      const int gy = gy0 - 1 + r;
      if (gy >= 0 && gy < Himg) {
        const float* p = pb + (size_t)gy * Wimg;
        #pragma unroll
        for (int ch = 0; ch < 8; ++ch) xr[r][ch] = p[(size_t)ch * HW];
      } else {
        #pragma unroll
        for (int ch = 0; ch < 8; ++ch) xr[r][ch] = 0.f;
      }
    }
    if (tid < 96) {
      const int gx = hside ? gx0 + TCOLS : gx0 - 1;
      const int gy = gy0 - 1 + hrow;
      if (gy >= 0 && gy < Himg && gx >= 0 && gx < Wimg) {
        const float* p = xin + ((size_t)img * C_IN + hkg * 8) * HW + (size_t)gy * Wimg + gx;
        #pragma unroll
        for (int ch = 0; ch < 8; ++ch) hr[ch] = p[(size_t)ch * HW];
      } else {
        #pragma unroll
        for (int ch = 0; ch < 8; ++ch) hr[ch] = 0.f;
      }
    }
  };

  auto WRITEX = [&]() {
    #pragma unroll
    for (int r = 0; r < HROWS; ++r) {
      uint4 cell;
      cell.x = pack2(xr[r][0], xr[r][1]); cell.y = pack2(xr[r][2], xr[r][3]);
      cell.z = pack2(xr[r][4], xr[r][5]); cell.w = pack2(xr[r][6], xr[r][7]);
      *(uint4*)(&Xs[kq * XKSTR + (r * HCOLS + 1 + xi) * 16]) = cell;
    }
    if (tid < 96) {
      uint4 cell;
      cell.x = pack2(hr[0], hr[1]); cell.y = pack2(hr[2], hr[3]);
      cell.z = pack2(hr[4], hr[5]); cell.w = pack2(hr[6], hr[7]);
      *(uint4*)(&Xs[hkg * XKSTR + (hrow * HCOLS + (hside ? HCOLS - 1 : 0)) * 16]) = cell;
    }
  };

  // tile decode: 2304 tiles of 4x64; 64/img (32 gy x 2 gx), gy fastest within strip
  auto TDEC = [&](int ts, int& img, int& gy0, int& gx0) {
    img = ts >> 6;
    const int rem = ts & 63;
    gy0 = (rem & 31) * TROWS;
    gx0 = (rem >> 5) * TCOLS;
  };

  // ---- prologue: stage tile 0 ----
  {
    int img, gy0, gx0;
    TDEC(s * 9, img, gy0, gx0);
    LOADX(img, gy0, gx0);
    WRITEX();
  }
  __syncthreads();   // drains Ws DMA + Xs ds_writes

  f32x16 acc[2];
  acc[0] = (f32x16)(0.f); acc[1] = (f32x16)(0.f);

  #pragma unroll 1
  for (int i = 0; i < 9; ++i) {
    int cimg, cgy0, cgx0;
    TDEC(s * 9 + i, cimg, cgy0, cgx0);

    if (i < 8) {   // T14: issue next tile's loads; consumed by WRITEX after compute
      int nimg, ngy0, ngx0;
      TDEC(s * 9 + i + 1, nimg, ngy0, ngx0);
      LOADX(nimg, ngy0, ngx0);
    }

    // ---- compute: 9 taps; wave = 32co x 1row x 64px; acc[pxhalf] ----
    #pragma unroll
    for (int t = 0; t < 9; ++t) {
      const int dy = (t >= 6) ? 2 : (t >= 3 ? 1 : 0);
      const int dx = t - dy * 3;
      const int brow = lkh * XKSTR + ((wn + dy) * HCOLS + dx + lpx) * 16;
      const int aoff = t * 8192 + lkh * 1024 + (wm * 32 + lpx) * 16;
      #pragma unroll
      for (int ks = 0; ks < 4; ++ks) {
        bf16x8 A  = *(const bf16x8*)&Ws[aoff + ks * 2048];
        bf16x8 B0 = *(const bf16x8*)&Xs[brow + ks * 2 * XKSTR];
        bf16x8 B1 = *(const bf16x8*)&Xs[brow + ks * 2 * XKSTR + 512];  // +32 cells
        acc[0] = __builtin_amdgcn_mfma_f32_32x32x16_bf16(A, B0, acc[0], 0, 0, 0);
        acc[1] = __builtin_amdgcn_mfma_f32_32x32x16_bf16(A, B1, acc[1], 0, 0, 0);
      }
    }

    // ---- epilogue: permlane32_swap -> 256B contiguous stores, wave-uniform bias ----
    // s_nop guards: backend hazard recognizer can't see inside asm; the sources are
    // fresh v_accvgpr_read results (VALU-write -> permlane-read wait states required).
    {
      const int y = cgy0 + wn;
      float* orow = out + (size_t)cimg * C_OUT * HW + (size_t)y * Wimg + cgx0 + lane;
      #pragma unroll
      for (int r = 0; r < 16; ++r) {
        const int cbase = coh * 64 + wm * 32 + (r & 3) + 8 * (r >> 2);
        unsigned ua, ub;
        { float f0 = acc[0][r], f1 = acc[1][r];
          ua = *(unsigned*)&f0; ub = *(unsigned*)&f1; }
        asm volatile("s_nop 4\n\t"
                     "v_permlane32_swap_b32 %0, %1\n\t"
                     "s_nop 2"
                     : "+v"(ua), "+v"(ub));
        // ua: px=lane @ cbase;  ub: px=lane @ cbase+4
        float fa = *(float*)&ua + bias[cbase];
        float fb = *(float*)&ub + bias[cbase + 4];
        orow[(size_t)cbase * HW]       = fa;   // 64 lanes x 4B = 256B contiguous
        orow[(size_t)(cbase + 4) * HW] = fb;
      }
    }
    acc[0] = (f32x16)(0.f); acc[1] = (f32x16)(0.f);

    if (i < 8) {
      // all waves done reading Xs (lgkm only — global stores stay in flight)
      asm volatile("s_waitcnt lgkmcnt(0)" ::: "memory");
      __builtin_amdgcn_s_barrier();
      __builtin_amdgcn_sched_barrier(0);
      WRITEX();
      asm volatile("s_waitcnt lgkmcnt(0)" ::: "memory");
      __builtin_amdgcn_s_barrier();
      __builtin_amdgcn_sched_barrier(0);
    }
  }
}

extern "C" void kernel_launch(void* const* d_in, const int* in_sizes, int n_in,
                              void* d_out, int out_size, void* d_ws, size_t ws_size,
                              hipStream_t stream) {
  const float* x    = (const float*)d_in[0];
  const float* w    = (const float*)d_in[1];
  const float* bias = (const float*)d_in[2];
  float* out = (float*)d_out;
  unsigned short* wt = (unsigned short*)d_ws;  // 147456 B

  wt_transform<<<(9 * C_OUT * C_IN + 255) / 256, 256, 0, stream>>>(w, wt);

  conv_mfma<<<dim3(512), 512, 0, stream>>>(x, wt, bias, out);
}